// Round 3
// baseline (6977.733 us; speedup 1.0000x reference)
//
#include <hip/hip_runtime.h>
#include <hip/hip_bf16.h>
#include <math.h>

#define B_ 64
#define S_ 512
#define I_ 256
#define H_ 1024
#define O_ 256

#define OUT_OFF (B_*O_)      // 16384 floats: final output
#define SLOT    (B_*H_)      // 65536 floats per hidden timestep slot

typedef __attribute__((ext_vector_type(8))) short bf16x8;  // 8 bf16 = 4 VGPRs
typedef __attribute__((ext_vector_type(4))) float f32x4;
typedef unsigned long long u64;

#define LDSK 1032            // padded row stride (1024 + 8 bf16): 2-way bank alias only (free)
#define NBLK 64              // persistent blocks (one 16-row W slice each)

#define AGENT_LD(p)     __hip_atomic_load((p),  __ATOMIC_RELAXED, __HIP_MEMORY_SCOPE_AGENT)
#define AGENT_ST(p, v)  __hip_atomic_store((p), (v), __ATOMIC_RELAXED, __HIP_MEMORY_SCOPE_AGENT)

// ---------------- zero hidden slot 0 (h0 = 0) + hbf0 + flag array ----------------
__global__ void k_zero(float* __restrict__ hid, float* __restrict__ hbf0,
                       unsigned int* __restrict__ flg) {
    int i = blockIdx.x * 256 + threadIdx.x;          // 64 blocks * 256 = 16384 float4
    ((float4*)hid)[i] = make_float4(0.f, 0.f, 0.f, 0.f);
    if (i < B_ * H_ * 2 / 16)                        // 8192 float4 = 128 KB bf16 zeros
        ((float4*)hbf0)[i] = make_float4(0.f, 0.f, 0.f, 0.f);
    if (i < 64)                                      // 256 flags (4 wave-groups x 64 slices)
        ((uint4*)flg)[i] = make_uint4(0u, 0u, 0u, 0u);
}

// ---------------- convert whh fp32 -> bf16 (natural row-major layout) ----------------
__global__ void k_cvt(const float* __restrict__ src, unsigned short* __restrict__ dst) {
    int i = blockIdx.x * 256 + threadIdx.x;          // 1024 blocks: 4 elems each
    float4 v = ((const float4*)src)[i];
    ushort4 o;
    o.x = __builtin_bit_cast(unsigned short, __float2bfloat16(v.x));
    o.y = __builtin_bit_cast(unsigned short, __float2bfloat16(v.y));
    o.z = __builtin_bit_cast(unsigned short, __float2bfloat16(v.z));
    o.w = __builtin_bit_cast(unsigned short, __float2bfloat16(v.w));
    ((ushort4*)dst)[i] = o;
}

// ---------------- generic transpose src[R][C] -> dst[C][R] ----------------
__global__ void k_transpose(const float* __restrict__ src, float* __restrict__ dst,
                            int R, int C) {
    __shared__ float tile[32][33];
    int c0 = blockIdx.x * 32, r0 = blockIdx.y * 32;
    int tx = threadIdx.x, ty = threadIdx.y;          // block (32,8)
#pragma unroll
    for (int j = 0; j < 32; j += 8)
        tile[ty + j][tx] = src[(size_t)(r0 + ty + j) * C + c0 + tx];
    __syncthreads();
#pragma unroll
    for (int j = 0; j < 32; j += 8)
        dst[(size_t)(c0 + ty + j) * R + r0 + tx] = tile[tx][ty + j];
}

// ---------------- x_proj: hid[t+1][b][h] = bias[h] + sum_i x[b][t][i] * W_ih[h][i] ----------------
__global__ __launch_bounds__(256) void k_xproj(const float* __restrict__ x,
                                               const float* __restrict__ wihT, // [I_][H_]
                                               const float* __restrict__ bias,
                                               float* __restrict__ hid) {
    const int t   = blockIdx.x;
    const int hq0 = blockIdx.y * 16;                 // h-quad base (64 h per tile)
    __shared__ float xs[B_][260];                    // +4 pad
    const int tid = threadIdx.x;

#pragma unroll
    for (int it = 0; it < 16; ++it) {
        int f4 = it * 256 + tid;
        int b = f4 >> 6, iq = f4 & 63;
        float4 v = ((const float4*)x)[(size_t)b * (S_ * I_ / 4) + t * (I_ / 4) + iq];
        *(float4*)&xs[b][iq * 4] = v;
    }
    __syncthreads();

    const int hq = tid & 15;
    const int b0 = (tid >> 4) * 4;
    float4 acc[4];
    float4 bs = ((const float4*)bias)[hq0 + hq];
#pragma unroll
    for (int i = 0; i < 4; ++i) acc[i] = bs;

    const float4* w4p = (const float4*)wihT;
#pragma unroll 4
    for (int k = 0; k < I_; ++k) {
        float4 w = w4p[(size_t)k * (H_ / 4) + hq0 + hq];
#pragma unroll
        for (int i = 0; i < 4; ++i) {
            float xv = xs[b0 + i][k];
            acc[i].x += xv * w.x; acc[i].y += xv * w.y;
            acc[i].z += xv * w.z; acc[i].w += xv * w.w;
        }
    }

    float4* out4 = (float4*)hid;
#pragma unroll
    for (int i = 0; i < 4; ++i)
        out4[(size_t)(t + 1) * (SLOT / 4) + (b0 + i) * (H_ / 4) + hq0 + hq] = acc[i];
}

// ---------------- persistent recurrence: lean flag sync, no cache fences ----------------
// 4 independent b-group pipelines (wave w of every block <-> wave w). Per step:
// poll 64 same-w flags (one 64-lane gather), MFMA with agent-scope (coherence-point) h loads,
// tanh + stores, vmcnt drain, publish own flag. No __syncthreads, no threadfence in loop.
__global__ __launch_bounds__(256) void k_rnn(
    const unsigned short* __restrict__ whhbf,   // [H_][H_] bf16
    unsigned short* __restrict__ h0,            // ping
    unsigned short* __restrict__ h1,            // pong
    float* __restrict__ hid,
    const float* __restrict__ fcwT,             // [H_][O_]
    const float* __restrict__ fcb,
    float* __restrict__ outp,
    unsigned int* __restrict__ flg)             // [4][64] wave-group x slice
{
    const int slice = blockIdx.x;
    const int tid   = threadIdx.x;
    __shared__ unsigned short Ws[16 * LDSK];    // 33 KB, resident all 512 steps
    __shared__ float hl[H_];                    // 4 KB, used only by fused fc

    // stage 16 W rows (32 KB contiguous) -> padded LDS, once
    {
        const float4* src = (const float4*)(whhbf + (size_t)slice * 16 * H_);
#pragma unroll
        for (int it = 0; it < 8; ++it) {
            int c = it * 256 + tid;              // 2048 chunks of 16B (8 bf16)
            float4 v = src[c];
            int row = c >> 7, off = (c & 127) * 8;
            *(float4*)&Ws[row * LDSK + off] = v;
        }
    }
    __syncthreads();

    const int w    = tid >> 6;                   // wave = b-tile (independent pipeline)
    const int lane = tid & 63;
    const int n    = lane & 15;                  // A-row (r_local) AND B-col (b_local)
    const int quad = lane >> 4;
    const int b    = w * 16 + n;
    const int r0   = slice * 16 + quad * 4;      // C/D: row = quad*4+reg, col = n

    const unsigned short* ap = &Ws[n * LDSK + quad * 8];
    const size_t boff = (size_t)b * H_ + quad * 8;   // B-fragment offset into h buffer
    const size_t hoff = (size_t)b * H_ + r0;         // hnext store offset
    const size_t bidx = (size_t)b * (H_ / 4) + (r0 >> 2);

    const u64* rb0 = (const u64*)(h0 + boff);    // fragment kk at u64 index kk*8 (+0,+1)
    const u64* rb1 = (const u64*)(h1 + boff);
    u64* wb0 = (u64*)(h0 + hoff);                // 8B-aligned (r0 multiple of 4 bf16)
    u64* wb1 = (u64*)(h1 + hoff);
    unsigned int* myflag = &flg[w * 64 + slice];
    const unsigned int* pollp = &flg[w * 64 + lane];

    for (int t = 0; t < S_; ++t) {
        // xp does not depend on the flags -> issue before the poll to hide its latency
        float4* slot1 = (float4*)(hid + (size_t)(t + 1) * SLOT);
        float4 xp = slot1[bidx];                 // x_proj + bias (private: plain load)

        // ---- wait for all same-w waves to have finished step t-1 (published t)
        if (t) {
            unsigned f = AGENT_LD(pollp);
            while (!__all(f >= (unsigned)t)) {
                __builtin_amdgcn_s_sleep(1);
                f = AGENT_LD(pollp);
            }
            asm volatile("" ::: "memory");       // no data loads hoisted above the poll
        }

        const u64* bq = (t & 1) ? rb1 : rb0;     // read h[t&1]
        u64* wq = (t & 1) ? wb0 : wb1;           // write h[(t+1)&1]

        f32x4 acc0 = {0.f, 0.f, 0.f, 0.f};
        f32x4 acc1 = {0.f, 0.f, 0.f, 0.f};       // 2 chains: halve dependent MFMA latency
#pragma unroll
        for (int kk = 0; kk < 32; kk += 2) {
            bf16x8 a0 = *(const bf16x8*)(ap + kk * 32);
            union { u64 u[2]; bf16x8 v; } b0c, b1c;
            b0c.u[0] = AGENT_LD(bq + kk * 8 + 0);
            b0c.u[1] = AGENT_LD(bq + kk * 8 + 1);
            acc0 = __builtin_amdgcn_mfma_f32_16x16x32_bf16(a0, b0c.v, acc0, 0, 0, 0);
            bf16x8 a1 = *(const bf16x8*)(ap + (kk + 1) * 32);
            b1c.u[0] = AGENT_LD(bq + (kk + 1) * 8 + 0);
            b1c.u[1] = AGENT_LD(bq + (kk + 1) * 8 + 1);
            acc1 = __builtin_amdgcn_mfma_f32_16x16x32_bf16(a1, b1c.v, acc1, 0, 0, 0);
        }

        float4 hv;
        hv.x = tanhf(acc0[0] + acc1[0] + xp.x);
        hv.y = tanhf(acc0[1] + acc1[1] + xp.y);
        hv.z = tanhf(acc0[2] + acc1[2] + xp.z);
        hv.w = tanhf(acc0[3] + acc1[3] + xp.w);

        if (t == S_ - 1) {
            // last step: fc reads this cross-block -> store via coherence point
            u64* ds = (u64*)&slot1[bidx];
            u64 d0 = (u64)__builtin_bit_cast(unsigned, hv.x) |
                     ((u64)__builtin_bit_cast(unsigned, hv.y) << 32);
            u64 d1 = (u64)__builtin_bit_cast(unsigned, hv.z) |
                     ((u64)__builtin_bit_cast(unsigned, hv.w) << 32);
            AGENT_ST(ds + 0, d0);
            AGENT_ST(ds + 1, d1);
        } else {
            slot1[bidx] = hv;                    // private: plain cached store

            unsigned short sx = __builtin_bit_cast(unsigned short, __float2bfloat16(hv.x));
            unsigned short sy = __builtin_bit_cast(unsigned short, __float2bfloat16(hv.y));
            unsigned short sz = __builtin_bit_cast(unsigned short, __float2bfloat16(hv.z));
            unsigned short sw = __builtin_bit_cast(unsigned short, __float2bfloat16(hv.w));
            u64 pk = (u64)sx | ((u64)sy << 16) | ((u64)sz << 32) | ((u64)sw << 48);
            AGENT_ST(wq, pk);                    // h_next: consumed cross-XCD -> coherent store
        }

        // ---- drain our stores to the coherence point, then publish
        asm volatile("s_waitcnt vmcnt(0)" ::: "memory");
        if (lane == 0) AGENT_ST(myflag, (unsigned)(t + 1));
    }

    // ---- fused final fc: block 'slice' handles batch bb = slice (NBLK == B_)
    {
        const int bb = slice;
        const int wgrp = bb >> 4;                // producer wave-group of batch bb
        const int lane = tid & 63;
        const unsigned int* fp = &flg[wgrp * 64 + lane];
        unsigned f = AGENT_LD(fp);
        while (!__all(f >= (unsigned)S_)) {
            __builtin_amdgcn_s_sleep(1);
            f = AGENT_LD(fp);
        }
        asm volatile("" ::: "memory");
        __syncthreads();

        const u64* hsrc = (const u64*)(hid + (size_t)S_ * SLOT + (size_t)bb * H_);
#pragma unroll
        for (int j = 0; j < 2; ++j) {
            u64 u = AGENT_LD(hsrc + tid * 2 + j);    // bypass stale local L2
            hl[tid * 4 + j * 2 + 0] = __builtin_bit_cast(float, (unsigned)(u & 0xffffffffu));
            hl[tid * 4 + j * 2 + 1] = __builtin_bit_cast(float, (unsigned)(u >> 32));
        }
        __syncthreads();

        float acc = fcb[tid];
#pragma unroll 4
        for (int k = 0; k < H_; ++k)
            acc += fcwT[(size_t)k * O_ + tid] * hl[k];
        outp[bb * O_ + tid] = acc;
    }
}

// ---------------- fallback path (only if cooperative launch is rejected) ----------------
__global__ __launch_bounds__(256) void k_step(
    const unsigned short* __restrict__ whhbf,
    const unsigned short* __restrict__ hprev,
    unsigned short* __restrict__ hnext,
    float* __restrict__ hid, int t)
{
    const int slice = blockIdx.x;
    __shared__ unsigned short Ws[16 * LDSK];
    const int tid = threadIdx.x;
    {
        const float4* src = (const float4*)(whhbf + (size_t)slice * 16 * H_);
#pragma unroll
        for (int it = 0; it < 8; ++it) {
            int c = it * 256 + tid;
            float4 v = src[c];
            int row = c >> 7, off = (c & 127) * 8;
            *(float4*)&Ws[row * LDSK + off] = v;
        }
    }
    __syncthreads();

    const int w    = tid >> 6;
    const int lane = tid & 63;
    const int n    = lane & 15;
    const int quad = lane >> 4;
    const int b = w * 16 + n;
    f32x4 acc = {0.f, 0.f, 0.f, 0.f};
    const unsigned short* ap = &Ws[n * LDSK + quad * 8];
    const unsigned short* bp = hprev + (size_t)b * H_ + quad * 8;
#pragma unroll
    for (int kk = 0; kk < 32; ++kk) {
        bf16x8 af = *(const bf16x8*)(ap + kk * 32);
        bf16x8 bf = *(const bf16x8*)(bp + kk * 32);
        acc = __builtin_amdgcn_mfma_f32_16x16x32_bf16(af, bf, acc, 0, 0, 0);
    }
    const int r0 = slice * 16 + quad * 4;
    float4* slot1 = (float4*)(hid + (size_t)(t + 1) * SLOT);
    size_t idx = (size_t)b * (H_ / 4) + (r0 >> 2);
    float4 xp = slot1[idx];
    float4 hv;
    hv.x = tanhf(acc[0] + xp.x);
    hv.y = tanhf(acc[1] + xp.y);
    hv.z = tanhf(acc[2] + xp.z);
    hv.w = tanhf(acc[3] + xp.w);
    slot1[idx] = hv;
    ushort4 hb;
    hb.x = __builtin_bit_cast(unsigned short, __float2bfloat16(hv.x));
    hb.y = __builtin_bit_cast(unsigned short, __float2bfloat16(hv.y));
    hb.z = __builtin_bit_cast(unsigned short, __float2bfloat16(hv.z));
    hb.w = __builtin_bit_cast(unsigned short, __float2bfloat16(hv.w));
    *(ushort4*)(hnext + (size_t)b * H_ + r0) = hb;
}

__global__ __launch_bounds__(256) void k_fc(const float* __restrict__ fcwT,
                                            const float* __restrict__ fcb,
                                            const float* __restrict__ hid,
                                            float* __restrict__ outp) {
    const int b = blockIdx.x;
    __shared__ float hl[H_];
    const int tid = threadIdx.x;
    ((float4*)hl)[tid] = ((const float4*)(hid + (size_t)S_ * SLOT + b * H_))[tid];
    __syncthreads();
    float acc = fcb[tid];
#pragma unroll 4
    for (int k = 0; k < H_; ++k)
        acc += fcwT[(size_t)k * O_ + tid] * hl[k];
    outp[b * O_ + tid] = acc;
}

extern "C" void kernel_launch(void* const* d_in, const int* in_sizes, int n_in,
                              void* d_out, int out_size, void* d_ws, size_t ws_size,
                              hipStream_t stream) {
    const float* x    = (const float*)d_in[0];
    const float* wih  = (const float*)d_in[1];
    const float* whh  = (const float*)d_in[2];
    const float* bias = (const float*)d_in[3];
    const float* fcw  = (const float*)d_in[4];
    const float* fcb  = (const float*)d_in[5];

    float* outp = (float*)d_out;
    float* hid  = outp + OUT_OFF;

    // ws layout: whhbf 2MB | hbf0 128KB | hbf1 128KB | wihT 1MB | fcwT 1MB | flg 1KB
    unsigned short* whhbf = (unsigned short*)d_ws;
    unsigned short* hbf0  = whhbf + (size_t)H_ * H_;
    unsigned short* hbf1  = hbf0 + (size_t)B_ * H_;
    float* wihT = (float*)(hbf1 + (size_t)B_ * H_);
    float* fcwT = wihT + (size_t)I_ * H_;
    unsigned int* flg = (unsigned int*)(fcwT + (size_t)H_ * O_);

    k_zero<<<SLOT / 4 / 256, 256, 0, stream>>>(hid, (float*)hbf0, flg);
    k_cvt<<<H_ * H_ / 4 / 256, 256, 0, stream>>>(whh, whhbf);
    k_transpose<<<dim3(I_ / 32, H_ / 32), dim3(32, 8), 0, stream>>>(wih, wihT, H_, I_);
    k_transpose<<<dim3(H_ / 32, O_ / 32), dim3(32, 8), 0, stream>>>(fcw, fcwT, O_, H_);

    k_xproj<<<dim3(S_, H_ / 64), 256, 0, stream>>>(x, wihT, bias, hid);

    void* args[] = {(void*)&whhbf, (void*)&hbf0, (void*)&hbf1, (void*)&hid,
                    (void*)&fcwT, (void*)&fcb, (void*)&outp, (void*)&flg};
    hipError_t e = hipLaunchCooperativeKernel((const void*)k_rnn, dim3(NBLK), dim3(256),
                                              args, 0, stream);
    if (e != hipSuccess) {
        // fallback: per-step launches (reproduces previous verified 4 ms path)
        unsigned short* hp[2] = {hbf0, hbf1};
        for (int t = 0; t < S_; ++t)
            k_step<<<64, 256, 0, stream>>>(whhbf, hp[t & 1], hp[(t + 1) & 1], hid, t);
        k_fc<<<B_, 256, 0, stream>>>(fcwT, fcb, hid, outp);
    }
}

// Round 4
// 6610.909 us; speedup vs baseline: 1.0555x; 1.0555x over previous
//
#include <hip/hip_runtime.h>
#include <hip/hip_bf16.h>
#include <math.h>

#define B_ 64
#define S_ 512
#define I_ 256
#define H_ 1024
#define O_ 256

#define OUT_OFF (B_*O_)      // 16384 floats: final output
#define SLOT    (B_*H_)      // 65536 floats per hidden timestep slot

typedef __attribute__((ext_vector_type(8))) short bf16x8;  // 8 bf16 = 4 VGPRs
typedef __attribute__((ext_vector_type(4))) float f32x4;
typedef unsigned long long u64;

#define LDSK 1032            // padded row stride (1024 + 8 bf16): 2-way bank alias only (free)
#define NBLK 64              // persistent blocks (one 16-row W slice each)

#define AGENT_LD(p)     __hip_atomic_load((p),  __ATOMIC_RELAXED, __HIP_MEMORY_SCOPE_AGENT)
#define AGENT_ST(p, v)  __hip_atomic_store((p), (v), __ATOMIC_RELAXED, __HIP_MEMORY_SCOPE_AGENT)

__device__ inline bf16x8 cvt8(float4 a, float4 b) {
    bf16x8 r;
    r[0] = (short)__builtin_bit_cast(unsigned short, __float2bfloat16(a.x));
    r[1] = (short)__builtin_bit_cast(unsigned short, __float2bfloat16(a.y));
    r[2] = (short)__builtin_bit_cast(unsigned short, __float2bfloat16(a.z));
    r[3] = (short)__builtin_bit_cast(unsigned short, __float2bfloat16(a.w));
    r[4] = (short)__builtin_bit_cast(unsigned short, __float2bfloat16(b.x));
    r[5] = (short)__builtin_bit_cast(unsigned short, __float2bfloat16(b.y));
    r[6] = (short)__builtin_bit_cast(unsigned short, __float2bfloat16(b.z));
    r[7] = (short)__builtin_bit_cast(unsigned short, __float2bfloat16(b.w));
    return r;
}

// ---------------- zero hidden slot 0 (h0 = 0) + flag array ----------------
__global__ void k_zero(float* __restrict__ hid, unsigned int* __restrict__ flg) {
    int i = blockIdx.x * 256 + threadIdx.x;          // 64 blocks * 256 = 16384 float4
    ((float4*)hid)[i] = make_float4(0.f, 0.f, 0.f, 0.f);
    if (i < 64)                                      // 256 flags (4 wave-groups x 64 slices)
        ((uint4*)flg)[i] = make_uint4(0u, 0u, 0u, 0u);
}

// ---------------- generic fp32 -> bf16 convert (count = grid*1024 elems) ----------------
__global__ void k_cvt(const float* __restrict__ src, unsigned short* __restrict__ dst) {
    int i = blockIdx.x * 256 + threadIdx.x;
    float4 v = ((const float4*)src)[i];
    ushort4 o;
    o.x = __builtin_bit_cast(unsigned short, __float2bfloat16(v.x));
    o.y = __builtin_bit_cast(unsigned short, __float2bfloat16(v.y));
    o.z = __builtin_bit_cast(unsigned short, __float2bfloat16(v.z));
    o.w = __builtin_bit_cast(unsigned short, __float2bfloat16(v.w));
    ((ushort4*)dst)[i] = o;
}

// ---------------- generic transpose src[R][C] -> dst[C][R] ----------------
__global__ void k_transpose(const float* __restrict__ src, float* __restrict__ dst,
                            int R, int C) {
    __shared__ float tile[32][33];
    int c0 = blockIdx.x * 32, r0 = blockIdx.y * 32;
    int tx = threadIdx.x, ty = threadIdx.y;          // block (32,8)
#pragma unroll
    for (int j = 0; j < 32; j += 8)
        tile[ty + j][tx] = src[(size_t)(r0 + ty + j) * C + c0 + tx];
    __syncthreads();
#pragma unroll
    for (int j = 0; j < 32; j += 8)
        dst[(size_t)(c0 + ty + j) * R + r0 + tx] = tile[tx][ty + j];
}

// ---------------- x_proj via MFMA: hid[t+1][b][h] = bias[h] + x[b][t][:] . wih[h][:]
// A = x rows (M=b), B = wih rows as cols (N=h), same fragment scheme as verified k_step.
__global__ __launch_bounds__(256) void k_xproj(const unsigned short* __restrict__ xbf,   // [B][S][I]
                                               const unsigned short* __restrict__ wihbf, // [H][I]
                                               const float* __restrict__ bias,
                                               float* __restrict__ hid) {
    const int t    = blockIdx.x;
    const int lane = threadIdx.x & 63;
    const int w    = threadIdx.x >> 6;          // wave -> h range [w*256, w*256+256)
    const int n    = lane & 15;
    const int quad = lane >> 4;

    // preload A-fragments: 4 b-tiles x 8 kk (x rows, read-once)
    bf16x8 afr[4][8];
#pragma unroll
    for (int bt = 0; bt < 4; ++bt) {
        const unsigned short* xp_ = xbf + ((size_t)(bt * 16 + n) * S_ + t) * I_ + quad * 8;
#pragma unroll
        for (int kk = 0; kk < 8; ++kk)
            afr[bt][kk] = *(const bf16x8*)(xp_ + kk * 32);
    }

    float* slot1 = hid + (size_t)(t + 1) * SLOT;
#pragma unroll 1
    for (int ht = 0; ht < 16; ++ht) {
        const int h0 = w * 256 + ht * 16;
        const unsigned short* wp = wihbf + (size_t)(h0 + n) * I_ + quad * 8;
        bf16x8 bfr[8];
#pragma unroll
        for (int kk = 0; kk < 8; ++kk) bfr[kk] = *(const bf16x8*)(wp + kk * 32);
        float bv = bias[h0 + n];
#pragma unroll
        for (int bt = 0; bt < 4; ++bt) {
            f32x4 acc = {0.f, 0.f, 0.f, 0.f};
#pragma unroll
            for (int kk = 0; kk < 8; ++kk)
                acc = __builtin_amdgcn_mfma_f32_16x16x32_bf16(afr[bt][kk], bfr[kk], acc, 0, 0, 0);
            const int b0 = bt * 16 + quad * 4;   // D: row = quad*4+reg (b), col = n (h)
#pragma unroll
            for (int r = 0; r < 4; ++r)
                slot1[(size_t)(b0 + r) * H_ + h0 + n] = acc[r] + bv;
        }
    }
}

// ---------------- fp32 fallback x_proj (used when workspace is small) ----------------
__global__ __launch_bounds__(256) void k_xproj_f32(const float* __restrict__ x,
                                                   const float* __restrict__ wihT, // [I_][H_]
                                                   const float* __restrict__ bias,
                                                   float* __restrict__ hid) {
    const int t   = blockIdx.x;
    const int hq0 = blockIdx.y * 16;
    __shared__ float xs[B_][260];
    const int tid = threadIdx.x;
#pragma unroll
    for (int it = 0; it < 16; ++it) {
        int f4 = it * 256 + tid;
        int b = f4 >> 6, iq = f4 & 63;
        float4 v = ((const float4*)x)[(size_t)b * (S_ * I_ / 4) + t * (I_ / 4) + iq];
        *(float4*)&xs[b][iq * 4] = v;
    }
    __syncthreads();
    const int hq = tid & 15;
    const int b0 = (tid >> 4) * 4;
    float4 acc[4];
    float4 bs = ((const float4*)bias)[hq0 + hq];
#pragma unroll
    for (int i = 0; i < 4; ++i) acc[i] = bs;
    const float4* w4p = (const float4*)wihT;
#pragma unroll 4
    for (int k = 0; k < I_; ++k) {
        float4 w = w4p[(size_t)k * (H_ / 4) + hq0 + hq];
#pragma unroll
        for (int i = 0; i < 4; ++i) {
            float xv = xs[b0 + i][k];
            acc[i].x += xv * w.x; acc[i].y += xv * w.y;
            acc[i].z += xv * w.z; acc[i].w += xv * w.w;
        }
    }
    float4* out4 = (float4*)hid;
#pragma unroll
    for (int i = 0; i < 4; ++i)
        out4[(size_t)(t + 1) * (SLOT / 4) + (b0 + i) * (H_ / 4) + hq0 + hq] = acc[i];
}

// ---------------- persistent recurrence ----------------
// h-state = fp32 hid slots (fresh address per step => consumer plain loads are
// guaranteed first-touch L2 misses served by the coherence point).
// xp reads + hv stores use agent scope (bypass L2) so slot t+1 lines never enter
// consumer L2 before their step. Flag skeleton identical to R3 (proven correct).
__global__ __launch_bounds__(256) void k_rnn(
    const unsigned short* __restrict__ whhbf,   // [H_][H_] bf16
    float* __restrict__ hid,
    const float* __restrict__ fcwT,             // [H_][O_]
    const float* __restrict__ fcb,
    float* __restrict__ outp,
    unsigned int* __restrict__ flg)             // [4][64] wave-group x slice
{
    const int slice = blockIdx.x;
    const int tid   = threadIdx.x;
    __shared__ unsigned short Ws[16 * LDSK];    // 33 KB, resident all 512 steps
    __shared__ float hl[H_];                    // 4 KB, fused fc only

    {
        const float4* src = (const float4*)(whhbf + (size_t)slice * 16 * H_);
#pragma unroll
        for (int it = 0; it < 8; ++it) {
            int c = it * 256 + tid;
            float4 v = src[c];
            int row = c >> 7, off = (c & 127) * 8;
            *(float4*)&Ws[row * LDSK + off] = v;
        }
    }
    __syncthreads();

    const int w    = tid >> 6;                   // wave = b-tile (independent pipeline)
    const int lane = tid & 63;
    const int n    = lane & 15;
    const int quad = lane >> 4;
    const int b    = w * 16 + n;
    const int r0   = slice * 16 + quad * 4;      // C/D: row = quad*4+reg, col = n

    const unsigned short* ap = &Ws[n * LDSK + quad * 8];
    const size_t hrow = (size_t)b * H_ + quad * 8;   // h-source row offset (fp32 elems)
    const size_t bidx = (size_t)b * (H_ / 4) + (r0 >> 2);
    unsigned int* myflag = &flg[w * 64 + slice];
    const unsigned int* pollp = &flg[w * 64 + lane];

    for (int t = 0; t < S_; ++t) {
        float* slot1 = hid + (size_t)(t + 1) * SLOT;
        u64* xpp = (u64*)slot1 + bidx * 2;
        // xp: agent loads issued before the poll (latency hidden; no L2 pollution)
        u64 xlo = AGENT_LD(xpp);
        u64 xhi = AGENT_LD(xpp + 1);

        if (t) {
            unsigned f = AGENT_LD(pollp);
            while (!__all(f >= (unsigned)t)) {
                __builtin_amdgcn_s_sleep(1);
                f = AGENT_LD(pollp);
            }
            asm volatile("" ::: "memory");       // data loads stay below the poll
        }

        // h-source: plain pipelined loads of slot t (first touch this step), cvt to bf16
        const float* hsrc = hid + (size_t)t * SLOT + hrow;
        f32x4 acc0 = {0.f, 0.f, 0.f, 0.f};
        f32x4 acc1 = {0.f, 0.f, 0.f, 0.f};
#pragma unroll 8
        for (int kk = 0; kk < 32; kk += 2) {
            float4 p0 = *(const float4*)(hsrc + kk * 32);
            float4 p1 = *(const float4*)(hsrc + kk * 32 + 4);
            float4 q0 = *(const float4*)(hsrc + (kk + 1) * 32);
            float4 q1 = *(const float4*)(hsrc + (kk + 1) * 32 + 4);
            bf16x8 a0 = *(const bf16x8*)(ap + kk * 32);
            bf16x8 a1 = *(const bf16x8*)(ap + (kk + 1) * 32);
            acc0 = __builtin_amdgcn_mfma_f32_16x16x32_bf16(a0, cvt8(p0, p1), acc0, 0, 0, 0);
            acc1 = __builtin_amdgcn_mfma_f32_16x16x32_bf16(a1, cvt8(q0, q1), acc1, 0, 0, 0);
        }

        float xpx = __builtin_bit_cast(float, (unsigned)(xlo & 0xffffffffu));
        float xpy = __builtin_bit_cast(float, (unsigned)(xlo >> 32));
        float xpz = __builtin_bit_cast(float, (unsigned)(xhi & 0xffffffffu));
        float xpw = __builtin_bit_cast(float, (unsigned)(xhi >> 32));
        float hvx = tanhf(acc0[0] + acc1[0] + xpx);
        float hvy = tanhf(acc0[1] + acc1[1] + xpy);
        float hvz = tanhf(acc0[2] + acc1[2] + xpz);
        float hvw = tanhf(acc0[3] + acc1[3] + xpw);

        // hv: both output and next step's h-source -> agent (coherence-point) store
        u64 d0 = (u64)__builtin_bit_cast(unsigned, hvx) |
                 ((u64)__builtin_bit_cast(unsigned, hvy) << 32);
        u64 d1 = (u64)__builtin_bit_cast(unsigned, hvz) |
                 ((u64)__builtin_bit_cast(unsigned, hvw) << 32);
        AGENT_ST(xpp, d0);
        AGENT_ST(xpp + 1, d1);

        asm volatile("s_waitcnt vmcnt(0)" ::: "memory");   // drain to coherence point
        if (lane == 0) AGENT_ST(myflag, (unsigned)(t + 1));
    }

    // ---- fused final fc: block 'slice' handles batch bb = slice (NBLK == B_)
    {
        const int bb = slice;
        const int wgrp = bb >> 4;                // producer wave-group of batch bb
        const unsigned int* fp = &flg[wgrp * 64 + lane];
        unsigned f = AGENT_LD(fp);
        while (!__all(f >= (unsigned)S_)) {
            __builtin_amdgcn_s_sleep(1);
            f = AGENT_LD(fp);
        }
        asm volatile("" ::: "memory");
        __syncthreads();

        // slot S_ lines: first plain touch by this XCD (loop read slots 0..S_-1 only)
        ((float4*)hl)[tid] = ((const float4*)(hid + (size_t)S_ * SLOT + (size_t)bb * H_))[tid];
        __syncthreads();

        float acc = fcb[tid];
#pragma unroll 4
        for (int k = 0; k < H_; ++k)
            acc += fcwT[(size_t)k * O_ + tid] * hl[k];
        outp[bb * O_ + tid] = acc;
    }
}

// ---------------- fallback per-step kernel (plain loads/stores; kernel-boundary coherence) ----------------
__global__ __launch_bounds__(256) void k_step2(const unsigned short* __restrict__ whhbf,
                                               float* __restrict__ hid, int t) {
    const int slice = blockIdx.x;
    __shared__ unsigned short Ws[16 * LDSK];
    const int tid = threadIdx.x;
    {
        const float4* src = (const float4*)(whhbf + (size_t)slice * 16 * H_);
#pragma unroll
        for (int it = 0; it < 8; ++it) {
            int c = it * 256 + tid;
            float4 v = src[c];
            int row = c >> 7, off = (c & 127) * 8;
            *(float4*)&Ws[row * LDSK + off] = v;
        }
    }
    __syncthreads();

    const int w = tid >> 6, lane = tid & 63;
    const int n = lane & 15, quad = lane >> 4;
    const int b = w * 16 + n;
    const int r0 = slice * 16 + quad * 4;
    const unsigned short* ap = &Ws[n * LDSK + quad * 8];
    const float* hsrc = hid + (size_t)t * SLOT + (size_t)b * H_ + quad * 8;

    f32x4 acc0 = {0.f, 0.f, 0.f, 0.f};
    f32x4 acc1 = {0.f, 0.f, 0.f, 0.f};
#pragma unroll 8
    for (int kk = 0; kk < 32; kk += 2) {
        float4 p0 = *(const float4*)(hsrc + kk * 32);
        float4 p1 = *(const float4*)(hsrc + kk * 32 + 4);
        float4 q0 = *(const float4*)(hsrc + (kk + 1) * 32);
        float4 q1 = *(const float4*)(hsrc + (kk + 1) * 32 + 4);
        bf16x8 a0 = *(const bf16x8*)(ap + kk * 32);
        bf16x8 a1 = *(const bf16x8*)(ap + (kk + 1) * 32);
        acc0 = __builtin_amdgcn_mfma_f32_16x16x32_bf16(a0, cvt8(p0, p1), acc0, 0, 0, 0);
        acc1 = __builtin_amdgcn_mfma_f32_16x16x32_bf16(a1, cvt8(q0, q1), acc1, 0, 0, 0);
    }
    float4* slot1 = (float4*)(hid + (size_t)(t + 1) * SLOT);
    size_t idx = (size_t)b * (H_ / 4) + (r0 >> 2);
    float4 xp = slot1[idx];
    float4 hv;
    hv.x = tanhf(acc0[0] + acc1[0] + xp.x);
    hv.y = tanhf(acc0[1] + acc1[1] + xp.y);
    hv.z = tanhf(acc0[2] + acc1[2] + xp.z);
    hv.w = tanhf(acc0[3] + acc1[3] + xp.w);
    slot1[idx] = hv;
}

__global__ __launch_bounds__(256) void k_fc(const float* __restrict__ fcwT,
                                            const float* __restrict__ fcb,
                                            const float* __restrict__ hid,
                                            float* __restrict__ outp) {
    const int b = blockIdx.x;
    __shared__ float hl[H_];
    const int tid = threadIdx.x;
    ((float4*)hl)[tid] = ((const float4*)(hid + (size_t)S_ * SLOT + b * H_))[tid];
    __syncthreads();
    float acc = fcb[tid];
#pragma unroll 4
    for (int k = 0; k < H_; ++k)
        acc += fcwT[(size_t)k * O_ + tid] * hl[k];
    outp[b * O_ + tid] = acc;
}

extern "C" void kernel_launch(void* const* d_in, const int* in_sizes, int n_in,
                              void* d_out, int out_size, void* d_ws, size_t ws_size,
                              hipStream_t stream) {
    const float* x    = (const float*)d_in[0];
    const float* wih  = (const float*)d_in[1];
    const float* whh  = (const float*)d_in[2];
    const float* bias = (const float*)d_in[3];
    const float* fcw  = (const float*)d_in[4];
    const float* fcb  = (const float*)d_in[5];

    float* outp = (float*)d_out;
    float* hid  = outp + OUT_OFF;

    // big ws layout: whhbf 2MB | xbf 16.8MB | wihbf 0.5MB | fcwT 1MB | flg 1KB  (~20.3MB)
    // small ws layout: whhbf 2MB | wihT 1MB | fcwT 1MB | flg 1KB  (~4.05MB)
    unsigned short* whhbf = (unsigned short*)d_ws;
    const size_t need_big = (size_t)H_ * H_ * 2 + (size_t)B_ * S_ * I_ * 2 +
                            (size_t)H_ * I_ * 2 + (size_t)H_ * O_ * 4 + 1024;
    const bool big = ws_size >= need_big;

    unsigned short* xbf   = whhbf + (size_t)H_ * H_;
    unsigned short* wihbf = xbf + (size_t)B_ * S_ * I_;
    float* fcwT_big = (float*)(wihbf + (size_t)H_ * I_);
    unsigned int* flg_big = (unsigned int*)(fcwT_big + (size_t)H_ * O_);

    float* wihT = (float*)(whhbf + (size_t)H_ * H_);
    float* fcwT_sm = wihT + (size_t)I_ * H_;
    unsigned int* flg_sm = (unsigned int*)(fcwT_sm + (size_t)H_ * O_);

    float* fcwT = big ? fcwT_big : fcwT_sm;
    unsigned int* flg = big ? flg_big : flg_sm;

    k_zero<<<SLOT / 4 / 256, 256, 0, stream>>>(hid, flg);
    k_cvt<<<H_ * H_ / 1024, 256, 0, stream>>>(whh, whhbf);
    k_transpose<<<dim3(H_ / 32, O_ / 32), dim3(32, 8), 0, stream>>>(fcw, fcwT, O_, H_);

    if (big) {
        k_cvt<<<B_ * S_ * I_ / 1024, 256, 0, stream>>>(x, xbf);
        k_cvt<<<H_ * I_ / 1024, 256, 0, stream>>>(wih, wihbf);
        k_xproj<<<S_, 256, 0, stream>>>(xbf, wihbf, bias, hid);
    } else {
        k_transpose<<<dim3(I_ / 32, H_ / 32), dim3(32, 8), 0, stream>>>(wih, wihT, H_, I_);
        k_xproj_f32<<<dim3(S_, H_ / 64), 256, 0, stream>>>(x, wihT, bias, hid);
    }

    void* args[] = {(void*)&whhbf, (void*)&hid, (void*)&fcwT, (void*)&fcb,
                    (void*)&outp, (void*)&flg};
    hipError_t e = hipLaunchCooperativeKernel((const void*)k_rnn, dim3(NBLK), dim3(256),
                                              args, 0, stream);
    if (e != hipSuccess) {
        for (int t = 0; t < S_; ++t)
            k_step2<<<64, 256, 0, stream>>>(whhbf, hid, t);
        k_fc<<<B_, 256, 0, stream>>>(fcwT, fcb, hid, outp);
    }
}